// Round 8
// baseline (104.894 us; speedup 1.0000x reference)
//
#include <hip/hip_runtime.h>
#include <math.h>

// SineGenVITS: B=16, L=131072, DIM=9. out = [sine (B,L,9) | uv (B,L,1) | noise (B,L,9)] f32.
//
// phase[b,t,d] = frac( k_d * C_t / SR + rand_ini[b,d] ),  C_t = sum f0[b,0..t] (f64 exact).
// The reference's integer wrap-shifts vanish mod 1; its own f32 error >> ours.
//
// R8: register-direct phase 2 (no LDS transpose). Each thread generates the
// 36 = 4 t x 9 d elements of the SAME 4 timesteps it scanned: p1/nm stay in
// registers, nz/out regions are contiguous 144 B (16B-aligned) per thread,
// (t_local,d) mapping is compile-time under full unroll. Plain stores (L2
// write-combining for the stride-144B pattern); L3 keeps nz resident across
// replays (R5: FETCH 41MB << 84MB of inputs).

#define Bq 16
#define Lq 131072
#define DIMq 9
#define CHUNK 1024
#define NCHUNK (Lq / CHUNK)  // 128
#define NBLK (Bq * NCHUNK)   // 2048
#define NT 256
#define PT 4                 // timesteps per thread
#define TQ 9                 // float4s per thread in phase 2 (4*9/4)

typedef float f32x4 __attribute__((ext_vector_type(4)));
typedef double f64x2 __attribute__((ext_vector_type(2)));

__global__ void __launch_bounds__(NT, 8) k_partials(
    const float* __restrict__ f0, double* __restrict__ part) {
  int bc = blockIdx.x;
  int b = bc >> 7, c = bc & 127;
  int tid = threadIdx.x, lane = tid & 63, wave = tid >> 6;
  const f32x4* p = (const f32x4*)(f0 + (size_t)b * Lq + (size_t)c * CHUNK);
  f32x4 x = p[tid];
  double s = ((double)x.x + (double)x.y) + ((double)x.z + (double)x.w);
#pragma unroll
  for (int d = 32; d > 0; d >>= 1) s += __shfl_xor(s, d, 64);
  __shared__ double ws[NT / 64];
  if (lane == 0) ws[wave] = s;
  __syncthreads();
  if (tid == 0) part[bc] = (ws[0] + ws[1]) + (ws[2] + ws[3]);
}

__global__ void __launch_bounds__(NT, 4) k_main(
    const float* __restrict__ f0, const float* __restrict__ rini,
    const float* __restrict__ nz, const double* __restrict__ part,
    float* __restrict__ out0, float* __restrict__ out1,
    float* __restrict__ out2) {
  int bc = blockIdx.x;
  int b = bc >> 7, c = bc & 127;
  int tid = threadIdx.x, lane = tid & 63, wave = tid >> 6;
  size_t t0g = (size_t)b * Lq + (size_t)c * CHUNK;

  __shared__ double wsum[NT / 64];

  // ---- phase 1: load f0 chunk, thread-local + wave f64 scan ----
  f32x4 fa = *(const f32x4*)(f0 + t0g + tid * PT);
  float fv[PT] = {fa.x, fa.y, fa.z, fa.w};
  double run = 0.0, inc[PT];
#pragma unroll
  for (int j = 0; j < PT; ++j) { run += (double)fv[j]; inc[j] = run; }
  double tot = run;
#pragma unroll
  for (int d = 1; d < 64; d <<= 1) {
    double o = __shfl_up(tot, d, 64);
    if (lane >= d) tot += o;
  }
  if (lane == 63) wsum[wave] = tot;
  __syncthreads();

  // ---- row prefix: reduce the c preceding chunk partials (2 per lane) ----
  f64x2 pp = ((const f64x2*)(part + (b << 7)))[lane];
  double pv = ((2 * lane < c) ? pp.x : 0.0) + ((2 * lane + 1 < c) ? pp.y : 0.0);
#pragma unroll
  for (int d = 32; d > 0; d >>= 1) pv += __shfl_xor(pv, d, 64);
  double wpre = 0.0;
  for (int w = 0; w < wave; ++w) wpre += wsum[w];
  double base = pv + wpre + (tot - run);  // exclusive prefix for this thread

  // ---- per-thread phase state in registers ----
  const double invsr = 1.0 / 22050.0;
  const float nampU = (float)(0.1 / 3.0);
  float p1r[PT], nmr[PT], uvv[PT];
#pragma unroll
  for (int j = 0; j < PT; ++j) {
    double ph = (base + inc[j]) * invsr;
    ph -= floor(ph);
    p1r[j] = (float)ph;
    bool v = fv[j] > 0.0f;
    nmr[j] = v ? 0.003f : -nampU;
    uvv[j] = v ? 1.0f : 0.0f;
  }
  f32x4 u0 = {uvv[0], uvv[1], uvv[2], uvv[3]};
  *(f32x4*)(out1 + t0g + tid * PT) = u0;

  float inir[DIMq];
#pragma unroll
  for (int d = 0; d < DIMq; ++d) inir[d] = rini[b * DIMq + d];  // uniform -> s_load

  // ---- phase 2: this thread's 4 t's = contiguous 36 floats (9 float4s) ----
  const f32x4* nzp = (const f32x4*)(nz + (t0g + (size_t)tid * PT) * DIMq);
  f32x4* o0p = (f32x4*)(out0 + (t0g + (size_t)tid * PT) * DIMq);
  f32x4* o2p = (f32x4*)(out2 + (t0g + (size_t)tid * PT) * DIMq);

#pragma unroll
  for (int q = 0; q < TQ; ++q) {
    f32x4 nzv = nzp[q];
    f32x4 r0, r2;
#pragma unroll
    for (int comp = 0; comp < 4; ++comp) {
      const int e = q * 4 + comp;       // 0..35, compile-time
      const int tl = e / 9;             // compile-time
      const int d = e - tl * 9;         // compile-time
      float p1 = p1r[tl], nm = nmr[tl];
      float ph = (float)(d + 1) * p1 + inir[d];
      ph -= floorf(ph);
      float s = __builtin_amdgcn_sinf(ph) * 0.1f;
      float noise = fabsf(nm) * nzv[comp];
      r2[comp] = noise;
      r0[comp] = (nm > 0.0f) ? s + noise : noise;
    }
    o0p[q] = r0;
    o2p[q] = r2;
  }
}

extern "C" void kernel_launch(void* const* d_in, const int* in_sizes, int n_in,
                              void* d_out, int out_size, void* d_ws, size_t ws_size,
                              hipStream_t stream) {
  const float* f0 = (const float*)d_in[0];
  const float* rini = (const float*)d_in[1];
  const float* nz = (const float*)d_in[2];
  float* out = (float*)d_out;
  float* out0 = out;                           // sine_waves (B,L,9)
  float* out1 = out + (size_t)Bq * Lq * DIMq;  // uv (B,L,1)
  float* out2 = out1 + (size_t)Bq * Lq;        // noise (B,L,9)
  double* part = (double*)d_ws;                // NBLK doubles = 16 KB

  k_partials<<<NBLK, NT, 0, stream>>>(f0, part);
  k_main<<<NBLK, NT, 0, stream>>>(f0, rini, nz, part, out0, out1, out2);
}

// Round 9
// 61.708 us; speedup vs baseline: 1.6998x; 1.6998x over previous
//
#include <hip/hip_runtime.h>
#include <math.h>

// SineGenVITS: B=16, L=131072, DIM=9. out = [sine (B,L,9) | uv (B,L,1) | noise (B,L,9)] f32.
//
// phase[b,t,d] = frac( k_d * C_t / SR + rand_ini[b,d] ),  C_t = sum f0[b,0..t] (f64 exact).
// The reference's integer wrap-shifts vanish mod 1; its own f32 error >> ours.
//
// R9 = R7 body (CHUNK=1024, LDS transpose, flat float4 phase 2 — R8 proved
// per-thread-contiguous stores cause 2.5x write amplification) fused into ONE
// kernel via decoupled lookback. Handshake is RELAXED agent atomics only
// (R5 showed acquire/release = whole-L2 inv storm, 153us; R6 proved relaxed +
// s_waitcnt vmcnt(0) publish ordering is correct). All 2048 blocks resident
// (LDS 8.3KB, 8/CU) so publishes happen concurrently after the ~1us prologue.
// Flags cleared by an 8KB hipMemsetAsync each call (no cross-call state).

#define Bq 16
#define Lq 131072
#define DIMq 9
#define CHUNK 1024
#define NCHUNK (Lq / CHUNK)  // 128
#define NBLK (Bq * NCHUNK)   // 2048
#define NT 256
#define PT 4                        // timesteps per thread
#define Q4 (CHUNK * DIMq / 4 / NT)  // 9 float4s per thread in phase 2

typedef float f32x4 __attribute__((ext_vector_type(4)));
typedef float f32x2 __attribute__((ext_vector_type(2)));
typedef double f64x2 __attribute__((ext_vector_type(2)));
typedef unsigned u32x2 __attribute__((ext_vector_type(2)));

__global__ void __launch_bounds__(NT, 8) k_fused(
    const float* __restrict__ f0, const float* __restrict__ rini,
    const float* __restrict__ nz, double* __restrict__ agg,
    unsigned* __restrict__ flags, float* __restrict__ out0,
    float* __restrict__ out1, float* __restrict__ out2) {
  int bc = blockIdx.x;
  int b = bc >> 7, c = bc & 127;
  int tid = threadIdx.x, lane = tid & 63, wave = tid >> 6;
  size_t t0g = (size_t)b * Lq + (size_t)c * CHUNK;

  __shared__ f32x2 ps[CHUNK];        // {p1 = frac(C_t/SR), nm = +-noise amp}
  __shared__ double wsum[NT / 64];

  // ---- phase 1: load f0 chunk, thread-local + wave f64 scan ----
  f32x4 fa = *(const f32x4*)(f0 + t0g + tid * PT);
  float fv[PT] = {fa.x, fa.y, fa.z, fa.w};
  double run = 0.0, inc[PT];
#pragma unroll
  for (int j = 0; j < PT; ++j) { run += (double)fv[j]; inc[j] = run; }
  double tot = run;
#pragma unroll
  for (int d = 1; d < 64; d <<= 1) {
    double o = __shfl_up(tot, d, 64);
    if (lane >= d) tot += o;
  }
  if (lane == 63) wsum[wave] = tot;
  __syncthreads();

  // ---- publish this chunk's aggregate (relaxed + vmcnt ordering) ----
  if (tid == 0) {
    double a = (wsum[0] + wsum[1]) + (wsum[2] + wsum[3]);
    __hip_atomic_store(&agg[bc], a, __ATOMIC_RELAXED, __HIP_MEMORY_SCOPE_AGENT);
    asm volatile("s_waitcnt vmcnt(0)" ::: "memory");
    __hip_atomic_store(&flags[bc], 1u, __ATOMIC_RELAXED, __HIP_MEMORY_SCOPE_AGENT);
  }

  // ---- lookback: 2 flags per lane, relaxed poll then masked reduce ----
  const unsigned* flp = flags + (b << 7) + 2 * lane;
  bool n0 = (2 * lane < c), n1 = (2 * lane + 1 < c);
  for (;;) {
    unsigned g0 = __hip_atomic_load(flp, __ATOMIC_RELAXED, __HIP_MEMORY_SCOPE_AGENT);
    unsigned g1 = __hip_atomic_load(flp + 1, __ATOMIC_RELAXED, __HIP_MEMORY_SCOPE_AGENT);
    if (__all((!n0 || g0) && (!n1 || g1))) break;
    __builtin_amdgcn_s_sleep(2);
  }
  f64x2 pp = ((const f64x2*)(agg + (b << 7)))[lane];
  double pv = (n0 ? pp.x : 0.0) + (n1 ? pp.y : 0.0);
#pragma unroll
  for (int d = 32; d > 0; d >>= 1) pv += __shfl_xor(pv, d, 64);
  double wpre = 0.0;
  for (int w = 0; w < wave; ++w) wpre += wsum[w];
  double base = pv + wpre + (tot - run);  // exclusive prefix for this thread

  const double invsr = 1.0 / 22050.0;
  const float nampU = (float)(0.1 / 3.0);
  float uvv[PT];
#pragma unroll
  for (int j = 0; j < PT; ++j) {
    double ph = (base + inc[j]) * invsr;
    ph -= floor(ph);
    bool v = fv[j] > 0.0f;
    f32x2 e = {(float)ph, v ? 0.003f : -nampU};
    ps[tid * PT + j] = e;
    uvv[j] = v ? 1.0f : 0.0f;
  }
  f32x4 u0 = {uvv[0], uvv[1], uvv[2], uvv[3]};
  __builtin_nontemporal_store(u0, (f32x4*)(out1 + t0g + tid * PT));

  float inir[DIMq];
#pragma unroll
  for (int d = 0; d < DIMq; ++d) inir[d] = rini[b * DIMq + d];  // uniform s_load
  __syncthreads();

  // ---- phase 2: flat float4 elementwise over chunk*9 elements ----
  const f32x4* nzc = (const f32x4*)(nz + t0g * DIMq);
  f32x4* o0c = (f32x4*)(out0 + t0g * DIMq);
  f32x4* o2c = (f32x4*)(out2 + t0g * DIMq);

  struct R { float r0, r2; };
  auto gen = [&](int t, int d, float nzv) -> R {
    f32x2 e = ps[t];
    float ph = (float)(d + 1) * e.x + inir[d];
    ph -= floorf(ph);
    float s = __builtin_amdgcn_sinf(ph) * 0.1f;
    float noise = fabsf(e.y) * nzv;
    R r;
    r.r2 = noise;
    r.r0 = (e.y > 0.0f) ? s + noise : noise;
    return r;
  };

#pragma unroll 3
  for (int w = 0; w < Q4; ++w) {
    int q = w * NT + tid;
    int e = q * 4;
    int t = (int)(((unsigned)e * 7282u) >> 16);  // e/9, exact for e<18432
    int d = e - t * 9;
    f32x4 nzv = nzc[q];  // plain load: keep nz L3-resident across replays
    R a = gen(t, d, nzv.x); if (++d == 9) { d = 0; ++t; }
    R bb = gen(t, d, nzv.y); if (++d == 9) { d = 0; ++t; }
    R cc = gen(t, d, nzv.z); if (++d == 9) { d = 0; ++t; }
    R dd = gen(t, d, nzv.w);
    f32x4 r0 = {a.r0, bb.r0, cc.r0, dd.r0};
    f32x4 r2 = {a.r2, bb.r2, cc.r2, dd.r2};
    __builtin_nontemporal_store(r0, &o0c[q]);
    __builtin_nontemporal_store(r2, &o2c[q]);
  }
}

extern "C" void kernel_launch(void* const* d_in, const int* in_sizes, int n_in,
                              void* d_out, int out_size, void* d_ws, size_t ws_size,
                              hipStream_t stream) {
  const float* f0 = (const float*)d_in[0];
  const float* rini = (const float*)d_in[1];
  const float* nz = (const float*)d_in[2];
  float* out = (float*)d_out;
  float* out0 = out;                           // sine_waves (B,L,9)
  float* out1 = out + (size_t)Bq * Lq * DIMq;  // uv (B,L,1)
  float* out2 = out1 + (size_t)Bq * Lq;        // noise (B,L,9)
  double* agg = (double*)d_ws;                 // NBLK doubles = 16 KB
  unsigned* flags = (unsigned*)((char*)d_ws + NBLK * sizeof(double));  // 8 KB

  (void)hipMemsetAsync(flags, 0, NBLK * sizeof(unsigned), stream);
  k_fused<<<NBLK, NT, 0, stream>>>(f0, rini, nz, agg, flags, out0, out1, out2);
}

// Round 10
// 47.125 us; speedup vs baseline: 2.2258x; 1.3095x over previous
//
#include <hip/hip_runtime.h>
#include <math.h>

// SineGenVITS: B=16, L=131072, DIM=9. out = [sine (B,L,9) | uv (B,L,1) | noise (B,L,9)] f32.
//
// phase[b,t,d] = frac( k_d * C_t / SR + rand_ini[b,d] ),  C_t = sum f0[b,0..t] (f64 exact).
// The reference's integer wrap-shifts vanish mod 1; its own f32 error >> ours.
//
// R10 = R7 split structure (lookback fusion refuted twice: R6 +10us, R9 +15us)
// with per-block work doubled: 512 threads / 2048 timesteps per block (same
// per-thread shape as R7: PT=4, 9 quads), halving per-block fixed costs
// (row-prefix reduce, rini load, block ramp). Flat float4 phase 2 (R8 proved
// per-thread-contiguous stores = 2.5x write amplification). NT stores; plain
// nz loads (L3 keeps nz resident across replays: R5 FETCH 41MB << inputs).

#define Bq 16
#define Lq 131072
#define DIMq 9
#define CHUNK 1024           // partial-sum granularity
#define NCHUNK (Lq / CHUNK)  // 128 partials per row
#define NPBLK (Bq * NCHUNK)  // 2048 partial blocks
#define BT 2048              // timesteps per k_main block (2 chunks)
#define NMBLK (Bq * (Lq / BT))  // 1024 main blocks
#define NT 256               // k_partials threads
#define NT2 512              // k_main threads
#define PT 4                 // timesteps per thread
#define Q4 (BT * DIMq / 4 / NT2)  // 9 float4s per thread in phase 2

typedef float f32x4 __attribute__((ext_vector_type(4)));
typedef float f32x2 __attribute__((ext_vector_type(2)));
typedef double f64x2 __attribute__((ext_vector_type(2)));

__global__ void __launch_bounds__(NT, 8) k_partials(
    const float* __restrict__ f0, double* __restrict__ part) {
  int bc = blockIdx.x;
  int b = bc >> 7, c = bc & 127;
  int tid = threadIdx.x, lane = tid & 63, wave = tid >> 6;
  const f32x4* p = (const f32x4*)(f0 + (size_t)b * Lq + (size_t)c * CHUNK);
  f32x4 x = p[tid];
  double s = ((double)x.x + (double)x.y) + ((double)x.z + (double)x.w);
#pragma unroll
  for (int d = 32; d > 0; d >>= 1) s += __shfl_xor(s, d, 64);
  __shared__ double ws[NT / 64];
  if (lane == 0) ws[wave] = s;
  __syncthreads();
  if (tid == 0) part[bc] = (ws[0] + ws[1]) + (ws[2] + ws[3]);
}

__global__ void __launch_bounds__(NT2, 8) k_main(
    const float* __restrict__ f0, const float* __restrict__ rini,
    const float* __restrict__ nz, const double* __restrict__ part,
    float* __restrict__ out0, float* __restrict__ out1,
    float* __restrict__ out2) {
  int bc = blockIdx.x;
  int b = bc >> 6, cp = bc & 63;  // cp indexes 2048-blocks; chunks 2cp,2cp+1
  int tid = threadIdx.x, lane = tid & 63, wave = tid >> 6;
  size_t t0g = (size_t)b * Lq + (size_t)cp * BT;

  __shared__ f32x2 ps[BT];  // {p1 = frac(C_t/SR), nm = +-noise amp}
  __shared__ double wsum[NT2 / 64];

  // ---- phase 1: load f0 (once), thread-local + wave f64 scan ----
  f32x4 fa = *(const f32x4*)(f0 + t0g + tid * PT);
  float fv[PT] = {fa.x, fa.y, fa.z, fa.w};
  double run = 0.0, inc[PT];
#pragma unroll
  for (int j = 0; j < PT; ++j) { run += (double)fv[j]; inc[j] = run; }
  double tot = run;
#pragma unroll
  for (int d = 1; d < 64; d <<= 1) {
    double o = __shfl_up(tot, d, 64);
    if (lane >= d) tot += o;
  }
  if (lane == 63) wsum[wave] = tot;
  __syncthreads();

  // ---- row prefix: both partials of lane's pair precede iff lane < cp ----
  f64x2 pp = ((const f64x2*)(part + (b << 7)))[lane];
  double pv = (lane < cp) ? (pp.x + pp.y) : 0.0;
#pragma unroll
  for (int d = 32; d > 0; d >>= 1) pv += __shfl_xor(pv, d, 64);
  double wpre = 0.0;
  for (int w = 0; w < wave; ++w) wpre += wsum[w];
  double base = pv + wpre + (tot - run);  // exclusive prefix for this thread

  const double invsr = 1.0 / 22050.0;
  const float nampU = (float)(0.1 / 3.0);
  float uvv[PT];
#pragma unroll
  for (int j = 0; j < PT; ++j) {
    double ph = __builtin_amdgcn_fract((base + inc[j]) * invsr);
    bool v = fv[j] > 0.0f;
    f32x2 e = {(float)ph, v ? 0.003f : -nampU};
    ps[tid * PT + j] = e;
    uvv[j] = v ? 1.0f : 0.0f;
  }
  f32x4 u0 = {uvv[0], uvv[1], uvv[2], uvv[3]};
  __builtin_nontemporal_store(u0, (f32x4*)(out1 + t0g + tid * PT));

  float inir[DIMq];
#pragma unroll
  for (int d = 0; d < DIMq; ++d) inir[d] = rini[b * DIMq + d];  // uniform s_load
  __syncthreads();

  // ---- phase 2: flat float4 elementwise over BT*9 elements ----
  const f32x4* nzc = (const f32x4*)(nz + t0g * DIMq);
  f32x4* o0c = (f32x4*)(out0 + t0g * DIMq);
  f32x4* o2c = (f32x4*)(out2 + t0g * DIMq);

  struct R { float r0, r2; };
  auto gen = [&](int t, int d, float nzv) -> R {
    f32x2 e = ps[t];
    float ph = __builtin_amdgcn_fractf((float)(d + 1) * e.x + inir[d]);
    float s = __builtin_amdgcn_sinf(ph) * 0.1f;
    float noise = fabsf(e.y) * nzv;
    R r;
    r.r2 = noise;
    r.r0 = (e.y > 0.0f) ? s + noise : noise;
    return r;
  };

#pragma unroll 3
  for (int w = 0; w < Q4; ++w) {
    int q = w * NT2 + tid;
    int e = q * 4;  // max 18431
    int t = (int)(((unsigned)e * 7282u) >> 16);  // e/9, exact for e<18432
    int d = e - t * 9;
    f32x4 nzv = nzc[q];  // plain load: keep nz L3-resident across replays
    R a = gen(t, d, nzv.x); if (++d == 9) { d = 0; ++t; }
    R bb = gen(t, d, nzv.y); if (++d == 9) { d = 0; ++t; }
    R cc = gen(t, d, nzv.z); if (++d == 9) { d = 0; ++t; }
    R dd = gen(t, d, nzv.w);
    f32x4 r0 = {a.r0, bb.r0, cc.r0, dd.r0};
    f32x4 r2 = {a.r2, bb.r2, cc.r2, dd.r2};
    __builtin_nontemporal_store(r0, &o0c[q]);
    __builtin_nontemporal_store(r2, &o2c[q]);
  }
}

extern "C" void kernel_launch(void* const* d_in, const int* in_sizes, int n_in,
                              void* d_out, int out_size, void* d_ws, size_t ws_size,
                              hipStream_t stream) {
  const float* f0 = (const float*)d_in[0];
  const float* rini = (const float*)d_in[1];
  const float* nz = (const float*)d_in[2];
  float* out = (float*)d_out;
  float* out0 = out;                           // sine_waves (B,L,9)
  float* out1 = out + (size_t)Bq * Lq * DIMq;  // uv (B,L,1)
  float* out2 = out1 + (size_t)Bq * Lq;        // noise (B,L,9)
  double* part = (double*)d_ws;                // NPBLK doubles = 16 KB

  k_partials<<<NPBLK, NT, 0, stream>>>(f0, part);
  k_main<<<NMBLK, NT2, 0, stream>>>(f0, rini, nz, part, out0, out1, out2);
}

// Round 11
// 46.887 us; speedup vs baseline: 2.2372x; 1.0051x over previous
//
#include <hip/hip_runtime.h>
#include <math.h>

// SineGenVITS: B=16, L=131072, DIM=9. out = [sine (B,L,9) | uv (B,L,1) | noise (B,L,9)] f32.
//
// phase[b,t,d] = frac( k_d * C_t / SR + rand_ini[b,d] ),  C_t = sum f0[b,0..t] (f64 exact).
// The reference's integer wrap-shifts vanish mod 1; its own f32 error >> ours.
//
// R11 = R7 k_main (CHUNK=1024/256thr proven best: R10's 2048/512 regressed)
// + wave-autonomous k_partials (one wave per chunk, no LDS/sync, 512 blocks
// -> dispatch cost ~halved). Lookback fusion refuted twice (R6/R9: coherence-
// point polling ~10-15us > launch overhead). Flat float4 phase 2 (R8: per-
// thread-contiguous = 2.5x write amplification). NT stores, plain nz loads
// (L3 keeps nz mostly resident across replays: R5 FETCH 41MB << 84MB inputs).

#define Bq 16
#define Lq 131072
#define DIMq 9
#define CHUNK 1024
#define NCHUNK (Lq / CHUNK)  // 128
#define NBLK (Bq * NCHUNK)   // 2048 chunks total
#define NT 256
#define PT 4                        // timesteps per thread in k_main
#define Q4 (CHUNK * DIMq / 4 / NT)  // 9 float4s per thread in phase 2

typedef float f32x4 __attribute__((ext_vector_type(4)));
typedef float f32x2 __attribute__((ext_vector_type(2)));
typedef double f64x2 __attribute__((ext_vector_type(2)));

// One wave per 1024-elem chunk: 4 f32x4 per lane, shfl reduce, lane-0 store.
__global__ void __launch_bounds__(NT, 8) k_partials(
    const float* __restrict__ f0, double* __restrict__ part) {
  int gw = blockIdx.x * (NT / 64) + (threadIdx.x >> 6);  // chunk id 0..2047
  int lane = threadIdx.x & 63;
  const f32x4* p = (const f32x4*)(f0 + (size_t)gw * CHUNK);
  f32x4 x0 = p[lane], x1 = p[lane + 64], x2 = p[lane + 128], x3 = p[lane + 192];
  double s = (((double)x0.x + (double)x0.y) + ((double)x0.z + (double)x0.w)) +
             (((double)x1.x + (double)x1.y) + ((double)x1.z + (double)x1.w)) +
             (((double)x2.x + (double)x2.y) + ((double)x2.z + (double)x2.w)) +
             (((double)x3.x + (double)x3.y) + ((double)x3.z + (double)x3.w));
#pragma unroll
  for (int d = 32; d > 0; d >>= 1) s += __shfl_xor(s, d, 64);
  if (lane == 0) part[gw] = s;
}

__global__ void __launch_bounds__(NT, 8) k_main(
    const float* __restrict__ f0, const float* __restrict__ rini,
    const float* __restrict__ nz, const double* __restrict__ part,
    float* __restrict__ out0, float* __restrict__ out1,
    float* __restrict__ out2) {
  int bc = blockIdx.x;
  int b = bc >> 7, c = bc & 127;
  int tid = threadIdx.x, lane = tid & 63, wave = tid >> 6;
  size_t t0g = (size_t)b * Lq + (size_t)c * CHUNK;

  __shared__ f32x2 ps[CHUNK];  // {p1 = frac(C_t/SR), nm = +-noise amp}
  __shared__ double wsum[NT / 64];

  // ---- phase 1: load f0 chunk, thread-local + wave f64 scan ----
  f32x4 fa = *(const f32x4*)(f0 + t0g + tid * PT);
  float fv[PT] = {fa.x, fa.y, fa.z, fa.w};
  double run = 0.0, inc[PT];
#pragma unroll
  for (int j = 0; j < PT; ++j) { run += (double)fv[j]; inc[j] = run; }
  double tot = run;
#pragma unroll
  for (int d = 1; d < 64; d <<= 1) {
    double o = __shfl_up(tot, d, 64);
    if (lane >= d) tot += o;
  }
  if (lane == 63) wsum[wave] = tot;
  __syncthreads();

  // ---- row prefix: reduce the c preceding chunk partials (2 per lane) ----
  f64x2 pp = ((const f64x2*)(part + (b << 7)))[lane];
  double pv = ((2 * lane < c) ? pp.x : 0.0) + ((2 * lane + 1 < c) ? pp.y : 0.0);
#pragma unroll
  for (int d = 32; d > 0; d >>= 1) pv += __shfl_xor(pv, d, 64);
  double wpre = 0.0;
  for (int w = 0; w < wave; ++w) wpre += wsum[w];
  double base = pv + wpre + (tot - run);  // exclusive prefix for this thread

  const double invsr = 1.0 / 22050.0;
  const float nampU = (float)(0.1 / 3.0);
  float uvv[PT];
#pragma unroll
  for (int j = 0; j < PT; ++j) {
    double ph = __builtin_amdgcn_fract((base + inc[j]) * invsr);
    bool v = fv[j] > 0.0f;
    f32x2 e = {(float)ph, v ? 0.003f : -nampU};
    ps[tid * PT + j] = e;
    uvv[j] = v ? 1.0f : 0.0f;
  }
  f32x4 u0 = {uvv[0], uvv[1], uvv[2], uvv[3]};
  __builtin_nontemporal_store(u0, (f32x4*)(out1 + t0g + tid * PT));

  float inir[DIMq];
#pragma unroll
  for (int d = 0; d < DIMq; ++d) inir[d] = rini[b * DIMq + d];  // uniform s_load
  __syncthreads();

  // ---- phase 2: flat float4 elementwise over chunk*9 elements ----
  const f32x4* nzc = (const f32x4*)(nz + t0g * DIMq);
  f32x4* o0c = (f32x4*)(out0 + t0g * DIMq);
  f32x4* o2c = (f32x4*)(out2 + t0g * DIMq);

  struct R { float r0, r2; };
  auto gen = [&](int t, int d, float nzv) -> R {
    f32x2 e = ps[t];
    float ph = __builtin_amdgcn_fractf((float)(d + 1) * e.x + inir[d]);
    float s = __builtin_amdgcn_sinf(ph) * 0.1f;
    float noise = fabsf(e.y) * nzv;
    R r;
    r.r2 = noise;
    r.r0 = (e.y > 0.0f) ? s + noise : noise;
    return r;
  };

  // software-pipelined: keep next quad's nz load in flight during compute
  f32x4 nzv = nzc[tid];
#pragma unroll 1
  for (int w = 0; w < Q4; ++w) {
    int q = w * NT + tid;
    f32x4 nznext;
    if (w + 1 < Q4) nznext = nzc[q + NT];
    int e = q * 4;
    int t = (int)(((unsigned)e * 7282u) >> 16);  // e/9, exact for e<18432
    int d = e - t * 9;
    R a = gen(t, d, nzv.x); if (++d == 9) { d = 0; ++t; }
    R bb = gen(t, d, nzv.y); if (++d == 9) { d = 0; ++t; }
    R cc = gen(t, d, nzv.z); if (++d == 9) { d = 0; ++t; }
    R dd = gen(t, d, nzv.w);
    f32x4 r0 = {a.r0, bb.r0, cc.r0, dd.r0};
    f32x4 r2 = {a.r2, bb.r2, cc.r2, dd.r2};
    __builtin_nontemporal_store(r0, &o0c[q]);
    __builtin_nontemporal_store(r2, &o2c[q]);
    nzv = nznext;
  }
}

extern "C" void kernel_launch(void* const* d_in, const int* in_sizes, int n_in,
                              void* d_out, int out_size, void* d_ws, size_t ws_size,
                              hipStream_t stream) {
  const float* f0 = (const float*)d_in[0];
  const float* rini = (const float*)d_in[1];
  const float* nz = (const float*)d_in[2];
  float* out = (float*)d_out;
  float* out0 = out;                           // sine_waves (B,L,9)
  float* out1 = out + (size_t)Bq * Lq * DIMq;  // uv (B,L,1)
  float* out2 = out1 + (size_t)Bq * Lq;        // noise (B,L,9)
  double* part = (double*)d_ws;                // NBLK doubles = 16 KB

  k_partials<<<NBLK / (NT / 64), NT, 0, stream>>>(f0, part);
  k_main<<<NBLK, NT, 0, stream>>>(f0, rini, nz, part, out0, out1, out2);
}